// Round 1
// baseline (919.865 us; speedup 1.0000x reference)
//
#include <hip/hip_runtime.h>
#include <cmath>

#define B_SZ 2
#define LSEQ 2048
#define DDIM 1024
#define NDIM 16
#define HDIM 128
#define MROWS (B_SZ * LSEQ) // 4096

// ---------------------------------------------------------------------------
// Generic fp32 GEMM: C = act(A @ B + bias [+ Cprev])
// A [M,K] row-major, B [K,N] row-major, C [M,N] row-major.
// Requires M % 64 == 0 and K % 16 == 0 (true for all call sites).
// N may be < 64 (guarded).
// ACT: 0=none, 1=relu, 2=tanh, 3=softplus
// ---------------------------------------------------------------------------
template <int ACT, bool ADD_PREV>
__global__ __launch_bounds__(256) void gemm_k(const float* __restrict__ A,
                                              const float* __restrict__ B,
                                              const float* __restrict__ bias,
                                              const float* __restrict__ Cprev,
                                              float* __restrict__ C,
                                              int M, int N, int K) {
    __shared__ float As[64][17];   // +1 pad: conflict-free reads
    __shared__ float Bs[16][64];

    const int tid = threadIdx.x;
    const int tx = tid & 15;   // n-group (16 groups of 4 cols)
    const int ty = tid >> 4;   // m-group (16 groups of 4 rows)
    const int bm = blockIdx.y * 64;
    const int bn = blockIdx.x * 64;

    float acc[4][4] = {};

    for (int k0 = 0; k0 < K; k0 += 16) {
        // Load A tile 64x16 (1024 elems, 4 per thread, coalesced in k)
        #pragma unroll
        for (int i = 0; i < 4; ++i) {
            int idx = tid + i * 256;
            int m = idx >> 4;
            int k = idx & 15;
            As[m][k] = A[(size_t)(bm + m) * K + k0 + k];
        }
        // Load B tile 16x64 (coalesced in n), guard n < N
        #pragma unroll
        for (int i = 0; i < 4; ++i) {
            int idx = tid + i * 256;
            int k = idx >> 6;
            int n = idx & 63;
            Bs[k][n] = (bn + n < N) ? B[(size_t)(k0 + k) * N + bn + n] : 0.f;
        }
        __syncthreads();

        #pragma unroll
        for (int k = 0; k < 16; ++k) {
            float a0 = As[ty * 4 + 0][k];
            float a1 = As[ty * 4 + 1][k];
            float a2 = As[ty * 4 + 2][k];
            float a3 = As[ty * 4 + 3][k];
            float4 bv = *reinterpret_cast<const float4*>(&Bs[k][tx * 4]);
            acc[0][0] += a0 * bv.x; acc[0][1] += a0 * bv.y; acc[0][2] += a0 * bv.z; acc[0][3] += a0 * bv.w;
            acc[1][0] += a1 * bv.x; acc[1][1] += a1 * bv.y; acc[1][2] += a1 * bv.z; acc[1][3] += a1 * bv.w;
            acc[2][0] += a2 * bv.x; acc[2][1] += a2 * bv.y; acc[2][2] += a2 * bv.z; acc[2][3] += a2 * bv.w;
            acc[3][0] += a3 * bv.x; acc[3][1] += a3 * bv.y; acc[3][2] += a3 * bv.z; acc[3][3] += a3 * bv.w;
        }
        __syncthreads();
    }

    #pragma unroll
    for (int i = 0; i < 4; ++i) {
        int m = bm + ty * 4 + i;
        #pragma unroll
        for (int j = 0; j < 4; ++j) {
            int n = bn + tx * 4 + j;
            if (n < N) {
                float v = acc[i][j];
                if (bias) v += bias[n];
                if (ADD_PREV) v += Cprev[(size_t)m * N + n];
                if (ACT == 1) v = fmaxf(v, 0.f);
                else if (ACT == 2) v = tanhf(v);
                else if (ACT == 3) v = (v > 0.f) ? v + log1pf(expf(-v)) : log1pf(expf(v));
                C[(size_t)m * N + n] = v;
            }
        }
    }
}

// ---------------------------------------------------------------------------
// Final fusion:
//   cb        = dot(Cm[row], Bm[row])
//   dA[d,n]   = exp(-celu(delta[row,d] * A[d,n]))
//   out[row,d] = x_trans*delta*cb + sum_n Cm[n]*dA[d,n]*h0[d,n]
//   last_h[b,d,n] = dA*h0 + x_trans*delta*Bm[n]        (only for l == L-1)
// ---------------------------------------------------------------------------
__global__ __launch_bounds__(256) void final_k(const float* __restrict__ x_trans,
                                               const float* __restrict__ delta,
                                               const float* __restrict__ Bm,
                                               const float* __restrict__ Cm,
                                               const float* __restrict__ A,
                                               const float* __restrict__ h0,
                                               float* __restrict__ out,
                                               float* __restrict__ last_h) {
    const int row = blockIdx.x;        // b*L + l, 0..4095
    const int tid = threadIdx.x;

    __shared__ float sC[NDIM], sB[NDIM];
    if (tid < NDIM) {
        sC[tid] = Cm[row * NDIM + tid];
        sB[tid] = Bm[row * NDIM + tid];
    }
    __syncthreads();

    float cb = 0.f;
    #pragma unroll
    for (int n = 0; n < NDIM; ++n) cb += sC[n] * sB[n];

    const int l = row & (LSEQ - 1);
    const int b = row >> 11;           // row / 2048
    const bool is_last = (l == LSEQ - 1);

    #pragma unroll
    for (int i = 0; i < DDIM / 256; ++i) {
        const int d = tid + i * 256;
        const float xt = x_trans[(size_t)row * DDIM + d];
        const float de = delta[(size_t)row * DDIM + d];
        const float xd = xt * de;
        float s = 0.f;
        #pragma unroll
        for (int n = 0; n < NDIM; ++n) {
            float z = de * A[d * NDIM + n];
            float c = (z > 0.f) ? z : expm1f(z);
            float da = expf(-c);
            float h0v = h0[d * NDIM + n];
            s += sC[n] * da * h0v;
            if (is_last) {
                last_h[((size_t)b * DDIM + d) * NDIM + n] = da * h0v + xd * sB[n];
            }
        }
        out[(size_t)row * DDIM + d] = xd * cb + s;
    }
}

extern "C" void kernel_launch(void* const* d_in, const int* in_sizes, int n_in,
                              void* d_out, int out_size, void* d_ws, size_t ws_size,
                              hipStream_t stream) {
    const float* x    = (const float*)d_in[0];
    const float* W1   = (const float*)d_in[1];
    const float* b1   = (const float*)d_in[2];
    const float* W2   = (const float*)d_in[3];
    const float* b2   = (const float*)d_in[4];
    const float* W3   = (const float*)d_in[5];
    const float* b3   = (const float*)d_in[6];
    const float* Wl1  = (const float*)d_in[7];
    const float* bl1  = (const float*)d_in[8];
    const float* Wl2  = (const float*)d_in[9];
    const float* bl2  = (const float*)d_in[10];
    const float* Wf1  = (const float*)d_in[11];
    const float* bf1  = (const float*)d_in[12];
    const float* Wf2  = (const float*)d_in[13];
    const float* bf2  = (const float*)d_in[14];
    const float* h0   = (const float*)d_in[15];  // state_init [1,D,N]
    const float* Amat = (const float*)d_in[16];  // A [D,N]

    float* out    = (float*)d_out;                          // [B,L,D]
    float* last_h = (float*)d_out + (size_t)B_SZ * LSEQ * DDIM; // [B,D,N]

    // Workspace layout (floats), with reuse:
    float* ws = (float*)d_ws;
    float* tmp1  = ws;                       // [4096,128] — also reused as accf
    float* tmp2  = tmp1 + MROWS * HDIM;      // [4096,128]
    float* lifted = tmp2 + MROWS * HDIM;     // [4096,1024] — reused as x_trans? no: separate below
    float* x_tr  = lifted;                   // x_trans reuses lifted slot (lifted dead after K4... see order)
    float* delta = lifted + (size_t)MROWS * DDIM;  // [4096,1024]
    float* Bmv   = delta + (size_t)MROWS * DDIM;   // [4096,16]
    float* Cmv   = Bmv + MROWS * NDIM;             // [4096,16]
    float* accf  = Cmv + MROWS * NDIM;             // [4096,128]
    // total: 2*524288 + 2*4194304 + 2*65536 + 524288 = ~41 MB

    const int M = MROWS;
    dim3 blk(256);

    // K1: tmp1 = relu(x @ Wl1 + bl1)            [4096,128], K=1024
    gemm_k<1, false><<<dim3(HDIM / 64, M / 64), blk, 0, stream>>>(x, Wl1, bl1, nullptr, tmp1, M, HDIM, DDIM);

    // K2: lifted = tanh(tmp1 @ Wl2 + bl2)       [4096,1024], K=128
    gemm_k<2, false><<<dim3(DDIM / 64, M / 64), blk, 0, stream>>>(tmp1, Wl2, bl2, nullptr, lifted, M, DDIM, HDIM);

    // K3: accf = x @ Wf1_top                    [4096,128], K=1024 (no bias/act)
    gemm_k<0, false><<<dim3(HDIM / 64, M / 64), blk, 0, stream>>>(x, Wf1, nullptr, nullptr, accf, M, HDIM, DDIM);

    // K4: tmp2 = relu(lifted @ Wf1_bot + bf1 + accf)   [4096,128], K=1024
    gemm_k<1, true><<<dim3(HDIM / 64, M / 64), blk, 0, stream>>>(lifted, Wf1 + (size_t)DDIM * HDIM, bf1, accf, tmp2, M, HDIM, DDIM);

    // K5: x_tr = tmp2 @ Wf2 + bf2               [4096,1024], K=128
    //     (x_tr aliases lifted; lifted is consumed by K4, safe)
    gemm_k<0, false><<<dim3(DDIM / 64, M / 64), blk, 0, stream>>>(tmp2, Wf2, bf2, nullptr, x_tr, M, DDIM, HDIM);

    // K6: delta = softplus(x_tr @ W1 + b1)      [4096,1024], K=1024
    gemm_k<3, false><<<dim3(DDIM / 64, M / 64), blk, 0, stream>>>(x_tr, W1, b1, nullptr, delta, M, DDIM, DDIM);

    // K7: Bm = x_tr @ W2 + b2                   [4096,16], K=1024
    gemm_k<0, false><<<dim3(1, M / 64), blk, 0, stream>>>(x_tr, W2, b2, nullptr, Bmv, M, NDIM, DDIM);

    // K8: Cm = x_tr @ W3 + b3                   [4096,16], K=1024
    gemm_k<0, false><<<dim3(1, M / 64), blk, 0, stream>>>(x_tr, W3, b3, nullptr, Cmv, M, NDIM, DDIM);

    // K9: final fusion → out + last_h
    final_k<<<dim3(MROWS), blk, 0, stream>>>(x_tr, delta, Bmv, Cmv, Amat, h0, out, last_h);
}

// Round 2
// 259.162 us; speedup vs baseline: 3.5494x; 3.5494x over previous
//
#include <hip/hip_runtime.h>
#include <cmath>

#define B_SZ 2
#define LSEQ 2048
#define DDIM 1024
#define NDIM 16
#define HDIM 128
#define MROWS (B_SZ * LSEQ)   // 4096
#define NBIG (DDIM + 2 * NDIM) // 1056

typedef __bf16 bf16x8 __attribute__((ext_vector_type(8)));
typedef __bf16 bf16x4 __attribute__((ext_vector_type(4)));
typedef float f32x4 __attribute__((ext_vector_type(4)));

// ---------------------------------------------------------------------------
// cast fp32 -> bf16, vectorized x4
// ---------------------------------------------------------------------------
__global__ __launch_bounds__(256) void cast_f32_bf16(const float* __restrict__ in,
                                                     __bf16* __restrict__ out, int n4) {
    int id = blockIdx.x * 256 + threadIdx.x;
    if (id < n4) {
        float4 v = ((const float4*)in)[id];
        bf16x4 o = {(__bf16)v.x, (__bf16)v.y, (__bf16)v.z, (__bf16)v.w};
        ((bf16x4*)out)[id] = o;
    }
}

// ---------------------------------------------------------------------------
// transpose + cast: in [K][N] fp32 (row stride N) -> out [N][K] bf16
// ---------------------------------------------------------------------------
__global__ __launch_bounds__(256) void tcast(const float* __restrict__ in,
                                             __bf16* __restrict__ out, int K, int N) {
    __shared__ float t[32][33];
    int tx = threadIdx.x & 31, ty = threadIdx.x >> 5; // 32 x 8
    int n0 = blockIdx.x * 32, k0 = blockIdx.y * 32;
    #pragma unroll
    for (int i = 0; i < 4; ++i) {
        int k = k0 + ty + i * 8, n = n0 + tx;
        t[ty + i * 8][tx] = (k < K && n < N) ? in[(size_t)k * N + n] : 0.f;
    }
    __syncthreads();
    #pragma unroll
    for (int i = 0; i < 4; ++i) {
        int n = n0 + ty + i * 8, k = k0 + tx;
        if (n < N && k < K) out[(size_t)n * K + k] = (__bf16)t[tx][ty + i * 8];
    }
}

__global__ void pack_bias(const float* __restrict__ b1, const float* __restrict__ b2,
                          const float* __restrict__ b3, float* __restrict__ out) {
    int i = blockIdx.x * 256 + threadIdx.x;
    if (i < NBIG)
        out[i] = (i < DDIM) ? b1[i] : (i < DDIM + NDIM) ? b2[i - DDIM] : b3[i - DDIM - NDIM];
}

// ---------------------------------------------------------------------------
// bf16 MFMA GEMM: C[M,Ntot] = act(A[M,K] @ B[K,Ntot] + bias [+ prev])
// B supplied TRANSPOSED: Bt [Ntot][K] bf16 (row stride ldb).
// Block 256 thr = 4 waves (2x2), tile BM x BN, BK=32, mfma 16x16x32.
// LDS row stride 40 bf16 (80B): 16 lanes of a fragment hit 8 distinct bank
// groups -> 2-way aliasing only (free per m136).
// ACT: 0 none, 1 relu(+prev), 2 tanh, 4 split128-relu (bias+relu col<128,
//      raw above), 5 split1024-softplus (softplus col<1024, linear above)
// ---------------------------------------------------------------------------
template <int BM, int BN, int ACT, bool ADD_PREV>
__global__ __launch_bounds__(256) void mm(const __bf16* __restrict__ A, int lda,
                                          const __bf16* __restrict__ Bt, int ldb, int Ntot,
                                          const float* __restrict__ bias,
                                          const __bf16* __restrict__ prev, int ldp,
                                          __bf16* __restrict__ C, int ldc, int K) {
    constexpr int WTM = BM / 2, WTN = BN / 2, FM = WTM / 16, FN = WTN / 16;
    __shared__ __bf16 As[BM * 40];
    __shared__ __bf16 Bs[BN * 40];
    const int tid = threadIdx.x;
    const int lane = tid & 63, w = tid >> 6;
    const int wr = w >> 1, wc = w & 1;
    const int g = lane >> 4, lr = lane & 15;
    const int bm = blockIdx.y * BM, bn = blockIdx.x * BN;

    f32x4 acc[FM][FN] = {};

    for (int k0 = 0; k0 < K; k0 += 32) {
        #pragma unroll
        for (int i = 0; i < BM / 64; ++i) {
            int c = tid + i * 256;
            int r = c >> 2, off = (c & 3) * 8;
            *(bf16x8*)&As[r * 40 + off] =
                *(const bf16x8*)&A[(size_t)(bm + r) * lda + k0 + off];
        }
        #pragma unroll
        for (int i = 0; i < BN / 64; ++i) {
            int c = tid + i * 256;
            int r = c >> 2, off = (c & 3) * 8;
            bf16x8 v = {};
            if (bn + r < Ntot) v = *(const bf16x8*)&Bt[(size_t)(bn + r) * ldb + k0 + off];
            *(bf16x8*)&Bs[r * 40 + off] = v;
        }
        __syncthreads();
        bf16x8 af[FM], bf[FN];
        #pragma unroll
        for (int m = 0; m < FM; ++m)
            af[m] = *(bf16x8*)&As[(wr * WTM + m * 16 + lr) * 40 + g * 8];
        #pragma unroll
        for (int n = 0; n < FN; ++n)
            bf[n] = *(bf16x8*)&Bs[(wc * WTN + n * 16 + lr) * 40 + g * 8];
        #pragma unroll
        for (int m = 0; m < FM; ++m)
            #pragma unroll
            for (int n = 0; n < FN; ++n)
                acc[m][n] = __builtin_amdgcn_mfma_f32_16x16x32_bf16(af[m], bf[n], acc[m][n], 0, 0, 0);
        __syncthreads();
    }

    // epilogue: C/D layout col=lane&15, row=(lane>>4)*4+reg  [m89 verified]
    #pragma unroll
    for (int m = 0; m < FM; ++m) {
        #pragma unroll
        for (int n = 0; n < FN; ++n) {
            #pragma unroll
            for (int r = 0; r < 4; ++r) {
                int grow = bm + wr * WTM + m * 16 + g * 4 + r;
                int gcol = bn + wc * WTN + n * 16 + lr;
                if (gcol < Ntot) {
                    float v = acc[m][n][r];
                    if (ACT == 0) {
                        v += bias[gcol];
                    } else if (ACT == 1) {
                        v += bias[gcol];
                        if (ADD_PREV) v += (float)prev[(size_t)grow * ldp + gcol];
                        v = fmaxf(v, 0.f);
                    } else if (ACT == 2) {
                        v = tanhf(v + bias[gcol]);
                    } else if (ACT == 4) {
                        if (gcol < HDIM) v = fmaxf(v + bias[gcol], 0.f);
                        // else: raw (x @ Wf1_top, no bias)
                    } else if (ACT == 5) {
                        v += bias[gcol];
                        if (gcol < DDIM) { // softplus
                            float e = __expf(-fabsf(v));
                            v = fmaxf(v, 0.f) + log1pf(e);
                        }
                    }
                    C[(size_t)grow * ldc + gcol] = (__bf16)v;
                }
            }
        }
    }
}

// ---------------------------------------------------------------------------
// Final fusion. db = [delta(softplus) | Bm | Cm] bf16, row stride NBIG.
//   out[row,d]   = x*de*(Cm.Bm) + sum_n Cm[n]*exp(-celu(de*A[d,n]))*h0[d,n]
//   last_h(l=L-1)= dA*h0 + x*de*Bm
// Fast path: if h0[d,:] == 0 the dA term vanishes entirely (0 * anything).
// ---------------------------------------------------------------------------
__global__ __launch_bounds__(256) void final_k(const __bf16* __restrict__ x_tr,
                                               const __bf16* __restrict__ db,
                                               const float* __restrict__ A,
                                               const float* __restrict__ h0,
                                               float* __restrict__ out,
                                               float* __restrict__ last_h) {
    const int row = blockIdx.x;
    const int tid = threadIdx.x;
    __shared__ float sC[NDIM], sB[NDIM];
    if (tid < NDIM) sB[tid] = (float)db[(size_t)row * NBIG + DDIM + tid];
    else if (tid >= 32 && tid < 32 + NDIM)
        sC[tid - 32] = (float)db[(size_t)row * NBIG + DDIM + NDIM + (tid - 32)];
    __syncthreads();
    float cb = 0.f;
    #pragma unroll
    for (int n = 0; n < NDIM; ++n) cb += sC[n] * sB[n];

    const int l = row & (LSEQ - 1);
    const int b = row >> 11;
    const bool is_last = (l == LSEQ - 1);

    #pragma unroll
    for (int i = 0; i < DDIM / 256; ++i) {
        const int d = tid + i * 256;
        const float xt = (float)x_tr[(size_t)row * DDIM + d];
        const float de = (float)db[(size_t)row * NBIG + d];
        const float xd = xt * de;
        const uint4* hu = (const uint4*)(h0 + d * NDIM);
        uint4 a0 = hu[0], a1 = hu[1], a2 = hu[2], a3 = hu[3];
        unsigned nz = a0.x | a0.y | a0.z | a0.w | a1.x | a1.y | a1.z | a1.w |
                      a2.x | a2.y | a2.z | a2.w | a3.x | a3.y | a3.z | a3.w;
        float s = 0.f;
        if (nz == 0u) {
            if (is_last) {
                #pragma unroll
                for (int n = 0; n < NDIM; ++n)
                    last_h[((size_t)b * DDIM + d) * NDIM + n] = xd * sB[n];
            }
        } else {
            const float* hf = h0 + d * NDIM;
            #pragma unroll
            for (int n = 0; n < NDIM; ++n) {
                float z = de * A[d * NDIM + n];
                float c = (z > 0.f) ? z : __expf(z) - 1.f; // celu
                float da = __expf(-c);
                float h0v = hf[n];
                s += sC[n] * da * h0v;
                if (is_last)
                    last_h[((size_t)b * DDIM + d) * NDIM + n] = da * h0v + xd * sB[n];
            }
        }
        out[(size_t)row * DDIM + d] = xd * cb + s;
    }
}

extern "C" void kernel_launch(void* const* d_in, const int* in_sizes, int n_in,
                              void* d_out, int out_size, void* d_ws, size_t ws_size,
                              hipStream_t stream) {
    const float* x   = (const float*)d_in[0];
    const float* W1  = (const float*)d_in[1];
    const float* b1  = (const float*)d_in[2];
    const float* W2  = (const float*)d_in[3];
    const float* b2  = (const float*)d_in[4];
    const float* W3  = (const float*)d_in[5];
    const float* b3  = (const float*)d_in[6];
    const float* Wl1 = (const float*)d_in[7];
    const float* bl1 = (const float*)d_in[8];
    const float* Wl2 = (const float*)d_in[9];
    const float* bl2 = (const float*)d_in[10];
    const float* Wf1 = (const float*)d_in[11];
    const float* bf1 = (const float*)d_in[12];
    const float* Wf2 = (const float*)d_in[13];
    const float* bf2 = (const float*)d_in[14];
    const float* h0  = (const float*)d_in[15];
    const float* Amat= (const float*)d_in[16];

    float* out    = (float*)d_out;
    float* last_h = (float*)d_out + (size_t)MROWS * DDIM;

    // --- workspace (bf16 bump allocator; all sizes multiples of 8 elems) ---
    __bf16* wsb = (__bf16*)d_ws;
    size_t o = 0;
    auto alloc = [&](size_t n) { __bf16* p = wsb + o; o += n; return p; };
    __bf16* x_bf   = alloc((size_t)MROWS * DDIM);   // x cast; reused as x_trb after G1
    __bf16* WaT    = alloc(256 * 1024);             // [Wl1 | Wf1_top]^T
    __bf16* Wf1bT  = alloc(128 * 1024);
    __bf16* Wl2T   = alloc(1024 * 128);
    __bf16* Wf2T   = alloc(1024 * 128);
    __bf16* WbigT  = alloc((size_t)NBIG * 1024);    // [W1 | W2 | W3]^T
    __bf16* tmp12  = alloc((size_t)MROWS * 256);    // [relu(x@Wl1+bl1) | x@Wf1_top]
    __bf16* lifted = alloc((size_t)MROWS * DDIM);
    __bf16* tmp2   = alloc((size_t)MROWS * HDIM);
    __bf16* db     = alloc((size_t)MROWS * NBIG);   // [delta | Bm | Cm]
    float*  bias_big = (float*)(wsb + o);           // NBIG floats
    __bf16* x_trb  = x_bf;                           // alias: x dead after G1

    // --- weight packing (transposed bf16) ---
    cast_f32_bf16<<<(MROWS * DDIM / 4 + 255) / 256, 256, 0, stream>>>(x, x_bf, MROWS * DDIM / 4);
    tcast<<<dim3(4, 32), 256, 0, stream>>>(Wl1, WaT, 1024, 128);
    tcast<<<dim3(4, 32), 256, 0, stream>>>(Wf1, WaT + 128 * 1024, 1024, 128);           // top half
    tcast<<<dim3(4, 32), 256, 0, stream>>>(Wf1 + (size_t)1024 * 128, Wf1bT, 1024, 128); // bottom half
    tcast<<<dim3(32, 4), 256, 0, stream>>>(Wl2, Wl2T, 128, 1024);
    tcast<<<dim3(32, 4), 256, 0, stream>>>(Wf2, Wf2T, 128, 1024);
    tcast<<<dim3(32, 32), 256, 0, stream>>>(W1, WbigT, 1024, 1024);
    tcast<<<dim3(1, 32), 256, 0, stream>>>(W2, WbigT + (size_t)1024 * 1024, 1024, 16);
    tcast<<<dim3(1, 32), 256, 0, stream>>>(W3, WbigT + (size_t)1040 * 1024, 1024, 16);
    pack_bias<<<5, 256, 0, stream>>>(b1, b2, b3, bias_big);

    // --- GEMM chain ---
    // G1: tmp12 = [relu(x@Wl1+bl1) | x@Wf1_top]      M=4096 N=256 K=1024
    mm<64, 64, 4, false><<<dim3(4, 64), 256, 0, stream>>>(
        x_bf, DDIM, WaT, 1024, 256, bl1, nullptr, 0, tmp12, 256, 1024);
    // G2: lifted = tanh(tmp12[:, :128] @ Wl2 + bl2)  M=4096 N=1024 K=128
    mm<128, 128, 2, false><<<dim3(8, 32), 256, 0, stream>>>(
        tmp12, 256, Wl2T, 128, 1024, bl2, nullptr, 0, lifted, DDIM, 128);
    // G3: tmp2 = relu(lifted@Wf1_bot + bf1 + tmp12[:,128:]) M=4096 N=128 K=1024
    mm<64, 64, 1, true><<<dim3(2, 64), 256, 0, stream>>>(
        lifted, DDIM, Wf1bT, 1024, 128, bf1, tmp12 + 128, 256, tmp2, HDIM, 1024);
    // G4: x_trb = tmp2 @ Wf2 + bf2                   M=4096 N=1024 K=128
    mm<128, 128, 0, false><<<dim3(8, 32), 256, 0, stream>>>(
        tmp2, HDIM, Wf2T, 128, 1024, bf2, nullptr, 0, x_trb, DDIM, 128);
    // G5: db = [softplus(.)|.|.] = x_trb @ [W1|W2|W3] + b M=4096 N=1056 K=1024
    mm<128, 128, 5, false><<<dim3((NBIG + 127) / 128, 32), 256, 0, stream>>>(
        x_trb, DDIM, WbigT, 1024, NBIG, bias_big, nullptr, 0, db, NBIG, 1024);

    // --- final fusion ---
    final_k<<<dim3(MROWS), 256, 0, stream>>>(x_trb, db, Amat, h0, out, last_h);
}

// Round 3
// 157.520 us; speedup vs baseline: 5.8397x; 1.6453x over previous
//
#include <hip/hip_runtime.h>
#include <cmath>

#define B_SZ 2
#define LSEQ 2048
#define DDIM 1024
#define NDIM 16
#define HDIM 128
#define MROWS (B_SZ * LSEQ)    // 4096
#define NBIG (DDIM + 2 * NDIM) // 1056

typedef __bf16 bf16x8 __attribute__((ext_vector_type(8)));
typedef __bf16 bf16x4 __attribute__((ext_vector_type(4)));
typedef float f32x4 __attribute__((ext_vector_type(4)));

// ---------------------------------------------------------------------------
// cast fp32 -> bf16, vectorized x4
// ---------------------------------------------------------------------------
__global__ __launch_bounds__(256) void cast_f32_bf16(const float* __restrict__ in,
                                                     __bf16* __restrict__ out, int n4) {
    int id = blockIdx.x * 256 + threadIdx.x;
    if (id < n4) {
        float4 v = ((const float4*)in)[id];
        bf16x4 o = {(__bf16)v.x, (__bf16)v.y, (__bf16)v.z, (__bf16)v.w};
        ((bf16x4*)out)[id] = o;
    }
}

// ---------------------------------------------------------------------------
// One fused weight-packing kernel: blockIdx.z selects the job.
// tcast: in [K][N] fp32 -> out [N][K] bf16 (32x32 tiles, 256 thr)
// ---------------------------------------------------------------------------
__device__ __forceinline__ void tcast_tile(const float* __restrict__ in,
                                           __bf16* __restrict__ out, int K, int N,
                                           int bx, int by, float (*t)[33]) {
    int tx = threadIdx.x & 31, ty = threadIdx.x >> 5;
    int n0 = bx * 32, k0 = by * 32;
    #pragma unroll
    for (int i = 0; i < 4; ++i) {
        int k = k0 + ty + i * 8, n = n0 + tx;
        t[ty + i * 8][tx] = (k < K && n < N) ? in[(size_t)k * N + n] : 0.f;
    }
    __syncthreads();
    #pragma unroll
    for (int i = 0; i < 4; ++i) {
        int n = n0 + ty + i * 8, k = k0 + tx;
        if (n < N && k < K) out[(size_t)n * K + k] = (__bf16)t[tx][ty + i * 8];
    }
}

__global__ __launch_bounds__(256) void pack_all(
    const float* W1, const float* W2, const float* W3, const float* Wl1,
    const float* Wl2, const float* Wf1, const float* Wf2,
    const float* b1, const float* b2, const float* b3,
    __bf16* WbigT, __bf16* WaT, __bf16* Wf1bT, __bf16* Wl2T, __bf16* Wf2T,
    float* bias_big) {
    __shared__ float t[32][33];
    const int bx = blockIdx.x, by = blockIdx.y, z = blockIdx.z;
    switch (z) {
        case 0: tcast_tile(W1, WbigT, 1024, 1024, bx, by, t); break;
        case 1: if (bx < 4) tcast_tile(Wl1, WaT, 1024, 128, bx, by, t); break;
        case 2: if (bx < 4) tcast_tile(Wf1, WaT + 128 * 1024, 1024, 128, bx, by, t); break;
        case 3: if (bx < 4) tcast_tile(Wf1 + (size_t)1024 * 128, Wf1bT, 1024, 128, bx, by, t); break;
        case 4: if (by < 4) tcast_tile(Wl2, Wl2T, 128, 1024, bx, by, t); break;
        case 5: if (by < 4) tcast_tile(Wf2, Wf2T, 128, 1024, bx, by, t); break;
        case 6: if (bx < 1) tcast_tile(W2, WbigT + (size_t)1024 * 1024, 1024, 16, bx, by, t); break;
        case 7: if (bx < 1) tcast_tile(W3, WbigT + (size_t)1040 * 1024, 1024, 16, bx, by, t); break;
        case 8: {
            if (by == 0 && bx < 5) {
                int i = bx * 256 + threadIdx.x;
                if (i < NBIG)
                    bias_big[i] = (i < DDIM) ? b1[i]
                                : (i < DDIM + NDIM) ? b2[i - DDIM] : b3[i - DDIM - NDIM];
            }
            break;
        }
    }
}

// ---------------------------------------------------------------------------
// bf16 MFMA GEMM: C[M,Ntot] = act(A[M,K] @ B[K,Ntot] + bias [+ prev])
// Bt [Ntot][K] bf16 (transposed). 256 thr = 4 waves (2x2 grid).
// Tile BM x BN, BK=32, mfma 16x16x32, LDS row stride 40 (2-way-free banks).
// ACT: 0 none, 1 relu(+prev), 2 tanh, 4 split128-relu, 5 split1024-softplus
// ---------------------------------------------------------------------------
template <int BM, int BN, int ACT, bool ADD_PREV, bool GUARDN>
__global__ __launch_bounds__(256) void mm(const __bf16* __restrict__ A, int lda,
                                          const __bf16* __restrict__ Bt, int ldb, int Ntot,
                                          const float* __restrict__ bias,
                                          const __bf16* __restrict__ prev, int ldp,
                                          __bf16* __restrict__ C, int ldc, int K) {
    constexpr int WTM = BM / 2, WTN = BN / 2, FM = WTM / 16, FN = WTN / 16;
    __shared__ __bf16 As[BM * 40];
    __shared__ __bf16 Bs[BN * 40];
    const int tid = threadIdx.x;
    const int lane = tid & 63, w = tid >> 6;
    const int wr = w >> 1, wc = w & 1;
    const int g = lane >> 4, lr = lane & 15;
    const int bm = blockIdx.y * BM, bn = blockIdx.x * BN;

    f32x4 acc[FM][FN] = {};

    for (int k0 = 0; k0 < K; k0 += 32) {
        #pragma unroll
        for (int i = 0; i < BM / 64; ++i) {
            int c = tid + i * 256;
            int r = c >> 2, off = (c & 3) * 8;
            *(bf16x8*)&As[r * 40 + off] =
                *(const bf16x8*)&A[(size_t)(bm + r) * lda + k0 + off];
        }
        #pragma unroll
        for (int i = 0; i < BN / 64; ++i) {
            int c = tid + i * 256;
            int r = c >> 2, off = (c & 3) * 8;
            bf16x8 v = {};
            if (!GUARDN || bn + r < Ntot)
                v = *(const bf16x8*)&Bt[(size_t)(bn + r) * ldb + k0 + off];
            *(bf16x8*)&Bs[r * 40 + off] = v;
        }
        __syncthreads();
        bf16x8 af[FM], bfr[FN];
        #pragma unroll
        for (int m = 0; m < FM; ++m)
            af[m] = *(bf16x8*)&As[(wr * WTM + m * 16 + lr) * 40 + g * 8];
        #pragma unroll
        for (int n = 0; n < FN; ++n)
            bfr[n] = *(bf16x8*)&Bs[(wc * WTN + n * 16 + lr) * 40 + g * 8];
        #pragma unroll
        for (int m = 0; m < FM; ++m)
            #pragma unroll
            for (int n = 0; n < FN; ++n)
                acc[m][n] = __builtin_amdgcn_mfma_f32_16x16x32_bf16(af[m], bfr[n], acc[m][n], 0, 0, 0);
        __syncthreads();
    }

    // epilogue: C/D layout col=lane&15, row=(lane>>4)*4+reg  [m89 verified]
    #pragma unroll
    for (int m = 0; m < FM; ++m) {
        #pragma unroll
        for (int n = 0; n < FN; ++n) {
            #pragma unroll
            for (int r = 0; r < 4; ++r) {
                int grow = bm + wr * WTM + m * 16 + g * 4 + r;
                int gcol = bn + wc * WTN + n * 16 + lr;
                if (!GUARDN || gcol < Ntot) {
                    float v = acc[m][n][r];
                    if (ACT == 0) {
                        v += bias[gcol];
                    } else if (ACT == 1) {
                        v += bias[gcol];
                        if (ADD_PREV) v += (float)prev[(size_t)grow * ldp + gcol];
                        v = fmaxf(v, 0.f);
                    } else if (ACT == 2) {
                        v = tanhf(v + bias[gcol]);
                    } else if (ACT == 4) {
                        if (gcol < HDIM) v = fmaxf(v + bias[gcol], 0.f);
                    } else if (ACT == 5) {
                        v += bias[gcol];
                        if (gcol < DDIM) {
                            float e = __expf(-fabsf(v));
                            v = fmaxf(v, 0.f) + log1pf(e);
                        }
                    }
                    C[(size_t)grow * ldc + gcol] = (__bf16)v;
                }
            }
        }
    }
}

// ---------------------------------------------------------------------------
// Final fusion, vectorized: 4 consecutive d per thread.
//   out[row,d]   = x*de*(Cm.Bm) + sum_n Cm[n]*exp(-celu(de*A[d,n]))*h0[d,n]
//   last_h(l=L-1)= dA*h0 + x*de*Bm
// h0[d,:]==0 fast path skips all transcendentals (0 * anything = 0).
// ---------------------------------------------------------------------------
__global__ __launch_bounds__(256) void final_k(const __bf16* __restrict__ x_tr,
                                               const __bf16* __restrict__ db,
                                               const float* __restrict__ A,
                                               const float* __restrict__ h0,
                                               float* __restrict__ out,
                                               float* __restrict__ last_h) {
    const int row = blockIdx.x;
    const int tid = threadIdx.x;
    __shared__ float sC[NDIM], sB[NDIM];
    if (tid < NDIM) sB[tid] = (float)db[(size_t)row * NBIG + DDIM + tid];
    else if (tid >= 32 && tid < 32 + NDIM)
        sC[tid - 32] = (float)db[(size_t)row * NBIG + DDIM + NDIM + (tid - 32)];
    __syncthreads();
    float cb = 0.f;
    #pragma unroll
    for (int n = 0; n < NDIM; ++n) cb += sC[n] * sB[n];

    const int l = row & (LSEQ - 1);
    const int b = row >> 11;
    const bool is_last = (l == LSEQ - 1);

    const int d0 = tid * 4;
    bf16x4 xv = *(const bf16x4*)&x_tr[(size_t)row * DDIM + d0];
    bf16x4 dv = *(const bf16x4*)&db[(size_t)row * NBIG + d0];
    float4 o;
    float* op = &o.x;
    #pragma unroll
    for (int j = 0; j < 4; ++j) {
        const int d = d0 + j;
        const float xd = (float)xv[j] * (float)dv[j];
        const uint4* hu = (const uint4*)(h0 + d * NDIM);
        uint4 a0 = hu[0], a1 = hu[1], a2 = hu[2], a3 = hu[3];
        unsigned nz = a0.x | a0.y | a0.z | a0.w | a1.x | a1.y | a1.z | a1.w |
                      a2.x | a2.y | a2.z | a2.w | a3.x | a3.y | a3.z | a3.w;
        float s = 0.f;
        if (nz == 0u) {
            if (is_last) {
                #pragma unroll
                for (int n = 0; n < NDIM; ++n)
                    last_h[((size_t)b * DDIM + d) * NDIM + n] = xd * sB[n];
            }
        } else {
            const float de = (float)dv[j];
            const float* hf = h0 + d * NDIM;
            #pragma unroll
            for (int n = 0; n < NDIM; ++n) {
                float z = de * A[d * NDIM + n];
                float c = (z > 0.f) ? z : __expf(z) - 1.f;
                float da = __expf(-c);
                float h0v = hf[n];
                s += sC[n] * da * h0v;
                if (is_last)
                    last_h[((size_t)b * DDIM + d) * NDIM + n] = da * h0v + xd * sB[n];
            }
        }
        op[j] = xd * cb + s;
    }
    *(float4*)&out[(size_t)row * DDIM + d0] = o;
}

extern "C" void kernel_launch(void* const* d_in, const int* in_sizes, int n_in,
                              void* d_out, int out_size, void* d_ws, size_t ws_size,
                              hipStream_t stream) {
    const float* x   = (const float*)d_in[0];
    const float* W1  = (const float*)d_in[1];
    const float* b1  = (const float*)d_in[2];
    const float* W2  = (const float*)d_in[3];
    const float* b2  = (const float*)d_in[4];
    const float* W3  = (const float*)d_in[5];
    const float* b3  = (const float*)d_in[6];
    const float* Wl1 = (const float*)d_in[7];
    const float* bl1 = (const float*)d_in[8];
    const float* Wl2 = (const float*)d_in[9];
    const float* bl2 = (const float*)d_in[10];
    const float* Wf1 = (const float*)d_in[11];
    const float* bf1 = (const float*)d_in[12];
    const float* Wf2 = (const float*)d_in[13];
    const float* bf2 = (const float*)d_in[14];
    const float* h0  = (const float*)d_in[15];
    const float* Amat= (const float*)d_in[16];

    float* out    = (float*)d_out;
    float* last_h = (float*)d_out + (size_t)MROWS * DDIM;

    __bf16* wsb = (__bf16*)d_ws;
    size_t o = 0;
    auto alloc = [&](size_t n) { __bf16* p = wsb + o; o += n; return p; };
    __bf16* x_bf   = alloc((size_t)MROWS * DDIM);   // reused as x_trb after G1
    __bf16* WaT    = alloc(256 * 1024);             // [Wl1 | Wf1_top]^T
    __bf16* Wf1bT  = alloc(128 * 1024);
    __bf16* Wl2T   = alloc(1024 * 128);
    __bf16* Wf2T   = alloc(1024 * 128);
    __bf16* WbigT  = alloc((size_t)NBIG * 1024);    // [W1 | W2 | W3]^T
    __bf16* tmp12  = alloc((size_t)MROWS * 256);    // [relu(x@Wl1+bl1) | x@Wf1_top]
    __bf16* lifted = alloc((size_t)MROWS * DDIM);
    __bf16* tmp2   = alloc((size_t)MROWS * HDIM);
    __bf16* db     = alloc((size_t)MROWS * NBIG);   // [delta | Bm | Cm]
    float*  bias_big = (float*)(wsb + o);
    __bf16* x_trb  = x_bf;

    // --- packing: 2 launches total ---
    cast_f32_bf16<<<dim3(MROWS * DDIM / 4 / 256), 256, 0, stream>>>(x, x_bf, MROWS * DDIM / 4);
    pack_all<<<dim3(32, 32, 9), 256, 0, stream>>>(W1, W2, W3, Wl1, Wl2, Wf1, Wf2,
                                                  b1, b2, b3,
                                                  WbigT, WaT, Wf1bT, Wl2T, Wf2T, bias_big);

    // --- GEMM chain (tiles sized for >=256-block grids) ---
    // G1: tmp12 = [relu(x@Wl1+bl1) | x@Wf1_top]   M=4096 N=256 K=1024, grid 256
    mm<64, 64, 4, false, false><<<dim3(4, 64), 256, 0, stream>>>(
        x_bf, DDIM, WaT, 1024, 256, bl1, nullptr, 0, tmp12, 256, 1024);
    // G2: lifted = tanh(tmp12[:,:128] @ Wl2 + bl2) M=4096 N=1024 K=128, grid 512
    mm<64, 128, 2, false, false><<<dim3(8, 64), 256, 0, stream>>>(
        tmp12, 256, Wl2T, 128, 1024, bl2, nullptr, 0, lifted, DDIM, 128);
    // G3: tmp2 = relu(lifted@Wf1_bot + bf1 + tmp12[:,128:]) M=4096 N=128 K=1024, grid 128
    mm<64, 64, 1, true, false><<<dim3(2, 64), 256, 0, stream>>>(
        lifted, DDIM, Wf1bT, 1024, 128, bf1, tmp12 + 128, 256, tmp2, HDIM, 1024);
    // G4: x_trb = tmp2 @ Wf2 + bf2                M=4096 N=1024 K=128, grid 512
    mm<64, 128, 0, false, false><<<dim3(8, 64), 256, 0, stream>>>(
        tmp2, HDIM, Wf2T, 128, 1024, bf2, nullptr, 0, x_trb, DDIM, 128);
    // G5: db = x_trb @ [W1|W2|W3] + b (softplus<1024) M=4096 N=1056 K=1024, grid 576
    mm<64, 128, 5, false, true><<<dim3(9, 64), 256, 0, stream>>>(
        x_trb, DDIM, WbigT, 1024, NBIG, bias_big, nullptr, 0, db, NBIG, 1024);

    // --- final fusion ---
    final_k<<<dim3(MROWS), 256, 0, stream>>>(x_trb, db, Amat, h0, out, last_h);
}

// Round 4
// 120.801 us; speedup vs baseline: 7.6147x; 1.3040x over previous
//
#include <hip/hip_runtime.h>
#include <cmath>

#define B_SZ 2
#define LSEQ 2048
#define DDIM 1024
#define NDIM 16
#define HDIM 128
#define MROWS (B_SZ * LSEQ)    // 4096
#define NBIG (DDIM + 2 * NDIM) // 1056
#define NPAD 1088              // NBIG padded to 64

typedef __bf16 bf16x8 __attribute__((ext_vector_type(8)));
typedef __bf16 bf16x4 __attribute__((ext_vector_type(4)));
typedef float f32x4 __attribute__((ext_vector_type(4)));

// ---------------------------------------------------------------------------
// async global->LDS, 16B per lane. LDS dest = wave-uniform base + lane*16.
// ---------------------------------------------------------------------------
__device__ __forceinline__ void glds16(const __bf16* g, __bf16* l) {
    __builtin_amdgcn_global_load_lds(
        (const __attribute__((address_space(1))) unsigned int*)g,
        (__attribute__((address_space(3))) unsigned int*)l, 16, 0, 0);
}

// ---------------------------------------------------------------------------
// cast fp32 -> bf16, vectorized x4
// ---------------------------------------------------------------------------
__global__ __launch_bounds__(256) void cast_f32_bf16(const float* __restrict__ in,
                                                     __bf16* __restrict__ out, int n4) {
    int id = blockIdx.x * 256 + threadIdx.x;
    if (id < n4) {
        float4 v = ((const float4*)in)[id];
        bf16x4 o = {(__bf16)v.x, (__bf16)v.y, (__bf16)v.z, (__bf16)v.w};
        ((bf16x4*)out)[id] = o;
    }
}

// ---------------------------------------------------------------------------
// Fused weight packing (blockIdx.z selects job); tcast: [K][N] f32 -> [N][K] bf16
// ---------------------------------------------------------------------------
__device__ __forceinline__ void tcast_tile(const float* __restrict__ in,
                                           __bf16* __restrict__ out, int K, int N,
                                           int bx, int by, float (*t)[33]) {
    int tx = threadIdx.x & 31, ty = threadIdx.x >> 5;
    int n0 = bx * 32, k0 = by * 32;
    #pragma unroll
    for (int i = 0; i < 4; ++i) {
        int k = k0 + ty + i * 8, n = n0 + tx;
        t[ty + i * 8][tx] = (k < K && n < N) ? in[(size_t)k * N + n] : 0.f;
    }
    __syncthreads();
    #pragma unroll
    for (int i = 0; i < 4; ++i) {
        int n = n0 + ty + i * 8, k = k0 + tx;
        if (n < N && k < K) out[(size_t)n * K + k] = (__bf16)t[tx][ty + i * 8];
    }
}

__global__ __launch_bounds__(256) void pack_all(
    const float* W1, const float* W2, const float* W3, const float* Wl1,
    const float* Wl2, const float* Wf1, const float* Wf2,
    const float* b1, const float* b2, const float* b3,
    __bf16* WbigT, __bf16* WaT, __bf16* Wf1bT, __bf16* Wl2T, __bf16* Wf2T,
    float* bias_big) {
    __shared__ float t[32][33];
    const int bx = blockIdx.x, by = blockIdx.y, z = blockIdx.z;
    switch (z) {
        case 0: tcast_tile(W1, WbigT, 1024, 1024, bx, by, t); break;
        case 1: if (bx < 4) tcast_tile(Wl1, WaT, 1024, 128, bx, by, t); break;
        case 2: if (bx < 4) tcast_tile(Wf1, WaT + 128 * 1024, 1024, 128, bx, by, t); break;
        case 3: if (bx < 4) tcast_tile(Wf1 + (size_t)1024 * 128, Wf1bT, 1024, 128, bx, by, t); break;
        case 4: if (by < 4) tcast_tile(Wl2, Wl2T, 128, 1024, bx, by, t); break;
        case 5: if (by < 4) tcast_tile(Wf2, Wf2T, 128, 1024, bx, by, t); break;
        case 6: if (bx < 1) tcast_tile(W2, WbigT + (size_t)1024 * 1024, 1024, 16, bx, by, t); break;
        case 7: if (bx < 1) tcast_tile(W3, WbigT + (size_t)1040 * 1024, 1024, 16, bx, by, t); break;
        case 8: {
            if (by == 0 && bx < 5) {
                int i = bx * 256 + threadIdx.x;
                if (i < NBIG)
                    bias_big[i] = (i < DDIM) ? b1[i]
                                : (i < DDIM + NDIM) ? b2[i - DDIM] : b3[i - DDIM - NDIM];
            }
            // zero the WbigT pad rows (1056..1087) so correctness run never sees NaN
            if (by == 1 && bx < 32) {
                int i = bx * 256 + threadIdx.x; // 0..8191 covers 32*1024/4... use 32 blocks of 256 over 32768 elems
                #pragma unroll
                for (int r = 0; r < 4; ++r) {
                    int e = i + r * 8192;
                    if (e < 32 * 1024) WbigT[(size_t)1056 * 1024 + e] = (__bf16)0.f;
                }
            }
            break;
        }
    }
}

// ---------------------------------------------------------------------------
// bf16 MFMA GEMM, 64x64 tile, BK=32, 4 waves (2x2), glds staging.
// LDS linear [64 rows][32 bf16]; global source chunk pre-swizzled with
// gs = s ^ ((r>>1)&3); reads apply same XOR (both-sides involution, rule #21).
// 1-D grid, bijective XCD swizzle (gridDim.x % 8 == 0 at all call sites).
// ACT: 0 bias, 1 relu(+prev), 2 fast-tanh, 4 split128-relu, 5 split1024-softplus
// ---------------------------------------------------------------------------
template <int ACT, bool ADD_PREV, bool GUARDN>
__global__ __launch_bounds__(256) void mm(const __bf16* __restrict__ A, int lda,
                                          const __bf16* __restrict__ Bt, int ldb, int Ntot,
                                          const float* __restrict__ bias,
                                          const __bf16* __restrict__ prev, int ldp,
                                          __bf16* __restrict__ C, int ldc, int K, int nbx) {
    __shared__ __bf16 As[64 * 32];
    __shared__ __bf16 Bs[64 * 32];
    const int tid = threadIdx.x;
    const int lane = tid & 63, w = tid >> 6;
    const int wr = w >> 1, wc = w & 1;
    const int g = lane >> 4, lr = lane & 15;

    const int NB = gridDim.x;
    const int aid = (blockIdx.x & 7) * (NB >> 3) + (blockIdx.x >> 3);
    const int bn = (aid % nbx) * 64, bm = (aid / nbx) * 64;

    // staging: thread t -> LDS byte t*16 (linear); source chunk swizzled
    const int sr = tid >> 2, sq = tid & 3;
    const int sgs = sq ^ ((sr >> 1) & 3);
    const __bf16* ga = &A[(size_t)(bm + sr) * lda + sgs * 8];
    const __bf16* gb = &Bt[(size_t)(bn + sr) * ldb + sgs * 8];
    __bf16* la = &As[w * 512]; // 512 bf16 = 1024 B per wave
    __bf16* lb = &Bs[w * 512];

    f32x4 acc[2][2] = {};
    const int ra0 = wr * 32 + lr, ra1 = ra0 + 16;
    const int rb0 = wc * 32 + lr, rb1 = rb0 + 16;
    #define SWZ(row, gg) ((row) * 32 + ((gg) ^ (((row) >> 1) & 3)) * 8)

    for (int k0 = 0; k0 < K; k0 += 32) {
        glds16(ga + k0, la);
        glds16(gb + k0, lb);
        __syncthreads(); // drains vmcnt -> LDS ready
        bf16x8 a0 = *(bf16x8*)&As[SWZ(ra0, g)];
        bf16x8 a1 = *(bf16x8*)&As[SWZ(ra1, g)];
        bf16x8 b0 = *(bf16x8*)&Bs[SWZ(rb0, g)];
        bf16x8 b1 = *(bf16x8*)&Bs[SWZ(rb1, g)];
        acc[0][0] = __builtin_amdgcn_mfma_f32_16x16x32_bf16(a0, b0, acc[0][0], 0, 0, 0);
        acc[0][1] = __builtin_amdgcn_mfma_f32_16x16x32_bf16(a0, b1, acc[0][1], 0, 0, 0);
        acc[1][0] = __builtin_amdgcn_mfma_f32_16x16x32_bf16(a1, b0, acc[1][0], 0, 0, 0);
        acc[1][1] = __builtin_amdgcn_mfma_f32_16x16x32_bf16(a1, b1, acc[1][1], 0, 0, 0);
        __syncthreads(); // LDS reuse fence
    }
    #undef SWZ

    #pragma unroll
    for (int m = 0; m < 2; ++m) {
        #pragma unroll
        for (int n = 0; n < 2; ++n) {
            #pragma unroll
            for (int r = 0; r < 4; ++r) {
                int grow = bm + wr * 32 + m * 16 + g * 4 + r;
                int gcol = bn + wc * 32 + n * 16 + lr;
                if (!GUARDN || gcol < Ntot) {
                    float v = acc[m][n][r];
                    if (ACT == 0) {
                        v += bias[gcol];
                    } else if (ACT == 1) {
                        v += bias[gcol];
                        if (ADD_PREV) v += (float)prev[(size_t)grow * ldp + gcol];
                        v = fmaxf(v, 0.f);
                    } else if (ACT == 2) { // fast tanh: 1 - 2/(1+e^2v)
                        v += bias[gcol];
                        float e = __expf(2.f * v);
                        v = 1.f - 2.f * __builtin_amdgcn_rcpf(e + 1.f);
                    } else if (ACT == 4) {
                        if (gcol < HDIM) v = fmaxf(v + bias[gcol], 0.f);
                    } else if (ACT == 5) {
                        v += bias[gcol];
                        if (gcol < DDIM) { // fast softplus
                            float e = __expf(-fabsf(v));
                            v = fmaxf(v, 0.f) + __logf(1.f + e);
                        }
                    }
                    C[(size_t)grow * ldc + gcol] = (__bf16)v;
                }
            }
        }
    }
}

// ---------------------------------------------------------------------------
// Final fusion (vectorized, h0==0 fast path)
// ---------------------------------------------------------------------------
__global__ __launch_bounds__(256) void final_k(const __bf16* __restrict__ x_tr,
                                               const __bf16* __restrict__ db,
                                               const float* __restrict__ A,
                                               const float* __restrict__ h0,
                                               float* __restrict__ out,
                                               float* __restrict__ last_h) {
    const int row = blockIdx.x;
    const int tid = threadIdx.x;
    __shared__ float sC[NDIM], sB[NDIM];
    if (tid < NDIM) sB[tid] = (float)db[(size_t)row * NBIG + DDIM + tid];
    else if (tid >= 32 && tid < 32 + NDIM)
        sC[tid - 32] = (float)db[(size_t)row * NBIG + DDIM + NDIM + (tid - 32)];
    __syncthreads();
    float cb = 0.f;
    #pragma unroll
    for (int n = 0; n < NDIM; ++n) cb += sC[n] * sB[n];

    const int l = row & (LSEQ - 1);
    const int b = row >> 11;
    const bool is_last = (l == LSEQ - 1);

    const int d0 = tid * 4;
    bf16x4 xv = *(const bf16x4*)&x_tr[(size_t)row * DDIM + d0];
    bf16x4 dv = *(const bf16x4*)&db[(size_t)row * NBIG + d0];
    float4 o;
    float* op = &o.x;
    #pragma unroll
    for (int j = 0; j < 4; ++j) {
        const int d = d0 + j;
        const float xd = (float)xv[j] * (float)dv[j];
        const uint4* hu = (const uint4*)(h0 + d * NDIM);
        uint4 a0 = hu[0], a1 = hu[1], a2 = hu[2], a3 = hu[3];
        unsigned nz = a0.x | a0.y | a0.z | a0.w | a1.x | a1.y | a1.z | a1.w |
                      a2.x | a2.y | a2.z | a2.w | a3.x | a3.y | a3.z | a3.w;
        float s = 0.f;
        if (nz == 0u) {
            if (is_last) {
                #pragma unroll
                for (int n = 0; n < NDIM; ++n)
                    last_h[((size_t)b * DDIM + d) * NDIM + n] = xd * sB[n];
            }
        } else {
            const float de = (float)dv[j];
            const float* hf = h0 + d * NDIM;
            #pragma unroll
            for (int n = 0; n < NDIM; ++n) {
                float z = de * A[d * NDIM + n];
                float c = (z > 0.f) ? z : __expf(z) - 1.f;
                float da = __expf(-c);
                float h0v = hf[n];
                s += sC[n] * da * h0v;
                if (is_last)
                    last_h[((size_t)b * DDIM + d) * NDIM + n] = da * h0v + xd * sB[n];
            }
        }
        op[j] = xd * cb + s;
    }
    *(float4*)&out[(size_t)row * DDIM + d0] = o;
}

extern "C" void kernel_launch(void* const* d_in, const int* in_sizes, int n_in,
                              void* d_out, int out_size, void* d_ws, size_t ws_size,
                              hipStream_t stream) {
    const float* x   = (const float*)d_in[0];
    const float* W1  = (const float*)d_in[1];
    const float* b1  = (const float*)d_in[2];
    const float* W2  = (const float*)d_in[3];
    const float* b2  = (const float*)d_in[4];
    const float* W3  = (const float*)d_in[5];
    const float* b3  = (const float*)d_in[6];
    const float* Wl1 = (const float*)d_in[7];
    const float* bl1 = (const float*)d_in[8];
    const float* Wl2 = (const float*)d_in[9];
    const float* bl2 = (const float*)d_in[10];
    const float* Wf1 = (const float*)d_in[11];
    const float* bf1 = (const float*)d_in[12];
    const float* Wf2 = (const float*)d_in[13];
    const float* bf2 = (const float*)d_in[14];
    const float* h0  = (const float*)d_in[15];
    const float* Amat= (const float*)d_in[16];

    float* out    = (float*)d_out;
    float* last_h = (float*)d_out + (size_t)MROWS * DDIM;

    __bf16* wsb = (__bf16*)d_ws;
    size_t o = 0;
    auto alloc = [&](size_t n) { __bf16* p = wsb + o; o += n; return p; };
    __bf16* x_bf   = alloc((size_t)MROWS * DDIM);   // reused as x_trb after G1
    __bf16* WaT    = alloc(256 * 1024);             // [Wl1 | Wf1_top]^T
    __bf16* Wf1bT  = alloc(128 * 1024);
    __bf16* Wl2T   = alloc(1024 * 128);
    __bf16* Wf2T   = alloc(1024 * 128);
    __bf16* WbigT  = alloc((size_t)NPAD * 1024);    // [W1 | W2 | W3 | pad]^T
    __bf16* tmp12  = alloc((size_t)MROWS * 256);    // [relu(x@Wl1+bl1) | x@Wf1_top]
    __bf16* lifted = alloc((size_t)MROWS * DDIM);
    __bf16* tmp2   = alloc((size_t)MROWS * HDIM);
    __bf16* db     = alloc((size_t)MROWS * NBIG);   // [delta | Bm | Cm]
    float*  bias_big = (float*)(wsb + o);
    __bf16* x_trb  = x_bf;

    cast_f32_bf16<<<dim3(MROWS * DDIM / 4 / 256), 256, 0, stream>>>(x, x_bf, MROWS * DDIM / 4);
    pack_all<<<dim3(32, 32, 9), 256, 0, stream>>>(W1, W2, W3, Wl1, Wl2, Wf1, Wf2,
                                                  b1, b2, b3,
                                                  WbigT, WaT, Wf1bT, Wl2T, Wf2T, bias_big);

    // G1: tmp12 = [relu(x@Wl1+bl1) | x@Wf1_top]     M=4096 N=256 K=1024, NB=256
    mm<4, false, false><<<dim3(4 * 64), 256, 0, stream>>>(
        x_bf, DDIM, WaT, 1024, 256, bl1, nullptr, 0, tmp12, 256, 1024, 4);
    // G2: lifted = tanh(tmp12[:,:128] @ Wl2 + bl2)  M=4096 N=1024 K=128, NB=1024
    mm<2, false, false><<<dim3(16 * 64), 256, 0, stream>>>(
        tmp12, 256, Wl2T, 128, 1024, bl2, nullptr, 0, lifted, DDIM, 128, 16);
    // G3: tmp2 = relu(lifted@Wf1_bot + bf1 + tmp12[:,128:]) M=4096 N=128 K=1024, NB=128
    mm<1, true, false><<<dim3(2 * 64), 256, 0, stream>>>(
        lifted, DDIM, Wf1bT, 1024, 128, bf1, tmp12 + 128, 256, tmp2, HDIM, 1024, 2);
    // G4: x_trb = tmp2 @ Wf2 + bf2                  M=4096 N=1024 K=128, NB=1024
    mm<0, false, false><<<dim3(16 * 64), 256, 0, stream>>>(
        tmp2, HDIM, Wf2T, 128, 1024, bf2, nullptr, 0, x_trb, DDIM, 128, 16);
    // G5: db = x_trb @ [W1|W2|W3] + b (softplus<1024) M=4096 N=1056(1088 pad) K=1024, NB=1088
    mm<5, false, true><<<dim3(17 * 64), 256, 0, stream>>>(
        x_trb, DDIM, WbigT, 1024, NBIG, bias_big, nullptr, 0, db, NBIG, 1024, 17);

    final_k<<<dim3(MROWS), 256, 0, stream>>>(x_trb, db, Amat, h0, out, last_h);
}

// Round 5
// 89.330 us; speedup vs baseline: 10.2974x; 1.3523x over previous
//
#include <hip/hip_runtime.h>
#include <cmath>

#define B_SZ 2
#define LSEQ 2048
#define DDIM 1024
#define NDIM 16
#define HDIM 128
#define MROWS (B_SZ * LSEQ)    // 4096
#define NBIG (DDIM + 2 * NDIM) // 1056
#define NPAD 1088              // NBIG padded to 64

typedef __bf16 bf16x8 __attribute__((ext_vector_type(8)));
typedef __bf16 bf16x4 __attribute__((ext_vector_type(4)));
typedef float f32x4 __attribute__((ext_vector_type(4)));

// async global->LDS, 16B/lane; LDS dest = wave-uniform base + lane*16
__device__ __forceinline__ void glds16(const __bf16* g, __bf16* l) {
    __builtin_amdgcn_global_load_lds(
        (const __attribute__((address_space(1))) unsigned int*)g,
        (__attribute__((address_space(3))) unsigned int*)l, 16, 0, 0);
}

// ---------------------------------------------------------------------------
// Fused preprocessing: weight transpose+cast, bias pack, x cast, h0 mask.
// ---------------------------------------------------------------------------
__device__ __forceinline__ void tcast_tile(const float* __restrict__ in,
                                           __bf16* __restrict__ out, int K, int N,
                                           int bx, int by, float (*t)[33]) {
    int tx = threadIdx.x & 31, ty = threadIdx.x >> 5;
    int n0 = bx * 32, k0 = by * 32;
    #pragma unroll
    for (int i = 0; i < 4; ++i) {
        int k = k0 + ty + i * 8, n = n0 + tx;
        t[ty + i * 8][tx] = (k < K && n < N) ? in[(size_t)k * N + n] : 0.f;
    }
    __syncthreads();
    #pragma unroll
    for (int i = 0; i < 4; ++i) {
        int n = n0 + ty + i * 8, k = k0 + tx;
        if (n < N && k < K) out[(size_t)n * K + k] = (__bf16)t[tx][ty + i * 8];
    }
}

__global__ __launch_bounds__(256) void pack_all(
    const float* W1, const float* W2, const float* W3, const float* Wl1,
    const float* Wl2, const float* Wf1, const float* Wf2,
    const float* b1, const float* b2, const float* b3,
    const float* x, const float* h0,
    __bf16* WbigT, __bf16* WaT, __bf16* Wf1bT, __bf16* Wl2T, __bf16* Wf2T,
    float* bias_big, __bf16* x_bf, unsigned* h0mask) {
    __shared__ float t[32][33];
    const int bx = blockIdx.x, by = blockIdx.y, z = blockIdx.z;
    const int tid = threadIdx.x;
    switch (z) {
        case 0: tcast_tile(W1, WbigT, 1024, 1024, bx, by, t); break;
        case 1: if (bx < 4) tcast_tile(Wl1, WaT, 1024, 128, bx, by, t); break;
        case 2: if (bx < 4) tcast_tile(Wf1, WaT + 128 * 1024, 1024, 128, bx, by, t); break;
        case 3: if (bx < 4) tcast_tile(Wf1 + (size_t)1024 * 128, Wf1bT, 1024, 128, bx, by, t); break;
        case 4: if (by < 4) tcast_tile(Wl2, Wl2T, 128, 1024, bx, by, t); break;
        case 5: if (by < 4) tcast_tile(Wf2, Wf2T, 128, 1024, bx, by, t); break;
        case 6: if (bx < 1) tcast_tile(W2, WbigT + (size_t)1024 * 1024, 1024, 16, bx, by, t); break;
        case 7: if (bx < 1) tcast_tile(W3, WbigT + (size_t)1040 * 1024, 1024, 16, bx, by, t); break;
        case 8: {
            if (by == 0 && bx < 5) {
                int i = bx * 256 + tid;
                if (i < NBIG)
                    bias_big[i] = (i < DDIM) ? b1[i]
                                : (i < DDIM + NDIM) ? b2[i - DDIM] : b3[i - DDIM - NDIM];
            }
            if (by == 1 && bx < 32) { // zero WbigT pad rows 1056..1087
                int i = bx * 256 + tid;
                #pragma unroll
                for (int r = 0; r < 4; ++r) {
                    int e = i + r * 8192;
                    if (e < 32 * 1024) WbigT[(size_t)1056 * 1024 + e] = (__bf16)0.f;
                }
            }
            break;
        }
        case 9: { // x cast fp32->bf16, 4 float4 per thread
            int id = (by * 32 + bx) * 256 + tid;
            #pragma unroll
            for (int j = 0; j < 4; ++j) {
                int e = id + j * 262144;
                float4 v = ((const float4*)x)[e];
                bf16x4 o2 = {(__bf16)v.x, (__bf16)v.y, (__bf16)v.z, (__bf16)v.w};
                ((bf16x4*)x_bf)[e] = o2;
            }
            break;
        }
        case 10: { // h0 nonzero bitmask: bit d set iff h0[d,:] has a nonzero
            if (bx == 0 && by == 0) {
                __shared__ unsigned sm[32];
                if (tid < 32) sm[tid] = 0u;
                __syncthreads();
                unsigned nib = 0;
                #pragma unroll
                for (int j = 0; j < 4; ++j) {
                    int d = tid * 4 + j;
                    const uint4* hu = (const uint4*)(h0 + d * NDIM);
                    uint4 a0 = hu[0], a1 = hu[1], a2 = hu[2], a3 = hu[3];
                    unsigned nz = a0.x | a0.y | a0.z | a0.w | a1.x | a1.y | a1.z | a1.w |
                                  a2.x | a2.y | a2.z | a2.w | a3.x | a3.y | a3.z | a3.w;
                    if (nz) nib |= (1u << j);
                }
                if (nib) atomicOr(&sm[(tid * 4) >> 5], nib << ((tid * 4) & 31));
                __syncthreads();
                if (tid < 32) h0mask[tid] = sm[tid];
            }
            break;
        }
    }
}

// ---------------------------------------------------------------------------
// bf16 MFMA GEMM, BMx64 tile, BK=64, double-buffered LDS, 2-phase prefetch.
// 4 waves 2x2 (wave tile BM/2 x 32). glds16 staging, linear LDS dest;
// 8-slot XOR swizzle (chunk ^ row&7) applied on the GLOBAL source and on the
// ds_read side (both-sides involution, rule #21) -> bank-balanced b128 reads.
// ACT: 0 bias, 1 relu(+prev), 2 fast-tanh, 4 split128-relu, 5 split1024-softplus
// ---------------------------------------------------------------------------
template <int BM, int ACT, bool ADD_PREV, bool GUARDN>
__global__ __launch_bounds__(256) void mm(const __bf16* __restrict__ A, int lda,
                                          const __bf16* __restrict__ Bt, int ldb, int Ntot,
                                          const float* __restrict__ bias,
                                          const __bf16* __restrict__ prev, int ldp,
                                          __bf16* __restrict__ C, int ldc, int K, int nbx) {
    constexpr int WM = BM / 2, FM = BM / 32;
    constexpr int ASZ = BM * 64;     // elements per A buffer
    __shared__ __bf16 As[2 * ASZ];
    __shared__ __bf16 Bs[2 * 4096];
    const int tid = threadIdx.x;
    const int lane = tid & 63, w = tid >> 6;
    const int wr = w >> 1, wc = w & 1;
    const int g = lane >> 4, lr = lane & 15;

    const int NB = gridDim.x;
    const int aid = (blockIdx.x & 7) * (NB >> 3) + (blockIdx.x >> 3);
    const int bn = (aid % nbx) * 64, bm = (aid / nbx) * BM;

    // staging: chunk D = i*256 + tid; LDS gets chunks linearly; global source
    // pre-swizzled: c = pos ^ (row & 7)
    auto stage = [&](int buf, int k0) {
        #pragma unroll
        for (int i = 0; i < BM / 32; ++i) {
            int D = i * 256 + tid;
            int row = D >> 3, pos = D & 7, c = pos ^ (row & 7);
            glds16(&A[(size_t)(bm + row) * lda + k0 + c * 8],
                   &As[buf * ASZ + (i * 256 + w * 64) * 8]);
        }
        #pragma unroll
        for (int i = 0; i < 2; ++i) {
            int D = i * 256 + tid;
            int row = D >> 3, pos = D & 7, c = pos ^ (row & 7);
            glds16(&Bt[(size_t)(bn + row) * ldb + k0 + c * 8],
                   &Bs[buf * 4096 + (i * 256 + w * 64) * 8]);
        }
    };

    f32x4 acc[FM][2] = {};
    const int x7 = lr & 7;
    const int ca[2] = {(g ^ x7) * 8, ((4 + g) ^ x7) * 8}; // col offset, half 0/1
    const int arow0 = wr * WM + lr;
    const int brow0 = wc * 32 + lr;

    const int nt = K >> 6;
    stage(0, 0);
    __syncthreads();
    for (int t = 0; t < nt; ++t) {
        if (t + 1 < nt) stage((t + 1) & 1, (t + 1) << 6);
        const __bf16* Ab = &As[(t & 1) * ASZ];
        const __bf16* Bb = &Bs[(t & 1) * 4096];
        bf16x8 af[FM][2], bfr[2][2];
        #pragma unroll
        for (int m = 0; m < FM; ++m)
            #pragma unroll
            for (int h = 0; h < 2; ++h)
                af[m][h] = *(const bf16x8*)&Ab[(arow0 + m * 16) * 64 + ca[h]];
        #pragma unroll
        for (int n = 0; n < 2; ++n)
            #pragma unroll
            for (int h = 0; h < 2; ++h)
                bfr[n][h] = *(const bf16x8*)&Bb[(brow0 + n * 16) * 64 + ca[h]];
        #pragma unroll
        for (int h = 0; h < 2; ++h)
            #pragma unroll
            for (int m = 0; m < FM; ++m)
                #pragma unroll
                for (int n = 0; n < 2; ++n)
                    acc[m][n] = __builtin_amdgcn_mfma_f32_16x16x32_bf16(
                        af[m][h], bfr[n][h], acc[m][n], 0, 0, 0);
        __syncthreads(); // drains prefetch vmcnt + fences LDS reuse
    }

    // epilogue: C/D layout col=lane&15, row=(lane>>4)*4+reg
    #pragma unroll
    for (int m = 0; m < FM; ++m) {
        #pragma unroll
        for (int n = 0; n < 2; ++n) {
            #pragma unroll
            for (int r = 0; r < 4; ++r) {
                int grow = bm + wr * WM + m * 16 + g * 4 + r;
                int gcol = bn + wc * 32 + n * 16 + lr;
                if (!GUARDN || gcol < Ntot) {
                    float v = acc[m][n][r];
                    if (ACT == 0) {
                        v += bias[gcol];
                    } else if (ACT == 1) {
                        v += bias[gcol];
                        if (ADD_PREV) v += (float)prev[(size_t)grow * ldp + gcol];
                        v = fmaxf(v, 0.f);
                    } else if (ACT == 2) { // fast tanh: 1 - 2/(1+e^2v)
                        v += bias[gcol];
                        float e = __expf(2.f * v);
                        v = 1.f - 2.f * __builtin_amdgcn_rcpf(e + 1.f);
                    } else if (ACT == 4) {
                        if (gcol < HDIM) v = fmaxf(v + bias[gcol], 0.f);
                    } else if (ACT == 5) {
                        v += bias[gcol];
                        if (gcol < DDIM) { // fast softplus
                            float e = __expf(-fabsf(v));
                            v = fmaxf(v, 0.f) + __logf(1.f + e);
                        }
                    }
                    C[(size_t)grow * ldc + gcol] = (__bf16)v;
                }
            }
        }
    }
}

// ---------------------------------------------------------------------------
// Final fusion; h0-zero rows resolved via precomputed 1024-bit mask.
// ---------------------------------------------------------------------------
__global__ __launch_bounds__(256) void final_k(const __bf16* __restrict__ x_tr,
                                               const __bf16* __restrict__ db,
                                               const float* __restrict__ A,
                                               const float* __restrict__ h0,
                                               const unsigned* __restrict__ h0mask,
                                               float* __restrict__ out,
                                               float* __restrict__ last_h) {
    const int row = blockIdx.x;
    const int tid = threadIdx.x;
    __shared__ float sC[NDIM], sB[NDIM];
    if (tid < NDIM) sB[tid] = (float)db[(size_t)row * NBIG + DDIM + tid];
    else if (tid >= 32 && tid < 32 + NDIM)
        sC[tid - 32] = (float)db[(size_t)row * NBIG + DDIM + NDIM + (tid - 32)];
    __syncthreads();
    float cb = 0.f;
    #pragma unroll
    for (int n = 0; n < NDIM; ++n) cb += sC[n] * sB[n];

    const int l = row & (LSEQ - 1);
    const int b = row >> 11;
    const bool is_last = (l == LSEQ - 1);

    const int d0 = tid * 4;
    bf16x4 xv = *(const bf16x4*)&x_tr[(size_t)row * DDIM + d0];
    bf16x4 dv = *(const bf16x4*)&db[(size_t)row * NBIG + d0];
    const unsigned nib = (h0mask[d0 >> 5] >> (d0 & 31)) & 0xFu;
    float4 o;
    float* op = &o.x;
    #pragma unroll
    for (int j = 0; j < 4; ++j) {
        const int d = d0 + j;
        const float xd = (float)xv[j] * (float)dv[j];
        float s = 0.f;
        if (!((nib >> j) & 1u)) {
            if (is_last) {
                #pragma unroll
                for (int n = 0; n < NDIM; ++n)
                    last_h[((size_t)b * DDIM + d) * NDIM + n] = xd * sB[n];
            }
        } else {
            const float de = (float)dv[j];
            const float* hf = h0 + d * NDIM;
            #pragma unroll
            for (int n = 0; n < NDIM; ++n) {
                float z = de * A[d * NDIM + n];
                float c = (z > 0.f) ? z : __expf(z) - 1.f;
                float da = __expf(-c);
                float h0v = hf[n];
                s += sC[n] * da * h0v;
                if (is_last)
                    last_h[((size_t)b * DDIM + d) * NDIM + n] = da * h0v + xd * sB[n];
            }
        }
        op[j] = xd * cb + s;
    }
    *(float4*)&out[(size_t)row * DDIM + d0] = o;
}

extern "C" void kernel_launch(void* const* d_in, const int* in_sizes, int n_in,
                              void* d_out, int out_size, void* d_ws, size_t ws_size,
                              hipStream_t stream) {
    const float* x   = (const float*)d_in[0];
    const float* W1  = (const float*)d_in[1];
    const float* b1  = (const float*)d_in[2];
    const float* W2  = (const float*)d_in[3];
    const float* b2  = (const float*)d_in[4];
    const float* W3  = (const float*)d_in[5];
    const float* b3  = (const float*)d_in[6];
    const float* Wl1 = (const float*)d_in[7];
    const float* bl1 = (const float*)d_in[8];
    const float* Wl2 = (const float*)d_in[9];
    const float* bl2 = (const float*)d_in[10];
    const float* Wf1 = (const float*)d_in[11];
    const float* bf1 = (const float*)d_in[12];
    const float* Wf2 = (const float*)d_in[13];
    const float* bf2 = (const float*)d_in[14];
    const float* h0  = (const float*)d_in[15];
    const float* Amat= (const float*)d_in[16];

    float* out    = (float*)d_out;
    float* last_h = (float*)d_out + (size_t)MROWS * DDIM;

    __bf16* wsb = (__bf16*)d_ws;
    size_t o = 0;
    auto alloc = [&](size_t n) { __bf16* p = wsb + o; o += n; return p; };
    __bf16* x_bf   = alloc((size_t)MROWS * DDIM);   // reused as x_trb after G1
    __bf16* WaT    = alloc(256 * 1024);             // [Wl1 | Wf1_top]^T
    __bf16* Wf1bT  = alloc(128 * 1024);
    __bf16* Wl2T   = alloc(1024 * 128);
    __bf16* Wf2T   = alloc(1024 * 128);
    __bf16* WbigT  = alloc((size_t)NPAD * 1024);    // [W1 | W2 | W3 | pad]^T
    __bf16* tmp12  = alloc((size_t)MROWS * 256);    // [relu(x@Wl1+bl1) | x@Wf1_top]
    __bf16* lifted = alloc((size_t)MROWS * DDIM);
    __bf16* tmp2   = alloc((size_t)MROWS * HDIM);
    __bf16* db     = alloc((size_t)MROWS * NBIG);   // [delta | Bm | Cm]
    float*  bias_big = (float*)(wsb + o); o += 2 * NPAD;
    unsigned* h0mask = (unsigned*)(wsb + o);
    __bf16* x_trb  = x_bf;

    pack_all<<<dim3(32, 32, 11), 256, 0, stream>>>(W1, W2, W3, Wl1, Wl2, Wf1, Wf2,
                                                   b1, b2, b3, x, h0,
                                                   WbigT, WaT, Wf1bT, Wl2T, Wf2T,
                                                   bias_big, x_bf, h0mask);

    // G1: tmp12 = [relu(x@Wl1+bl1) | x@Wf1_top]     M=4096 N=256 K=1024, 256 blk
    mm<64, 4, false, false><<<dim3(4 * 64), 256, 0, stream>>>(
        x_bf, DDIM, WaT, 1024, 256, bl1, nullptr, 0, tmp12, 256, 1024, 4);
    // G2: lifted = tanh(tmp12[:,:128] @ Wl2 + bl2)  M=4096 N=1024 K=128, 1024 blk
    mm<64, 2, false, false><<<dim3(16 * 64), 256, 0, stream>>>(
        tmp12, 256, Wl2T, 128, 1024, bl2, nullptr, 0, lifted, DDIM, 128, 16);
    // G3: tmp2 = relu(lifted@Wf1_bot + bf1 + tmp12[:,128:]) M=4096 N=128 K=1024, 256 blk
    mm<32, 1, true, false><<<dim3(2 * 128), 256, 0, stream>>>(
        lifted, DDIM, Wf1bT, 1024, 128, bf1, tmp12 + 128, 256, tmp2, HDIM, 1024, 2);
    // G4: x_trb = tmp2 @ Wf2 + bf2                  M=4096 N=1024 K=128, 1024 blk
    mm<64, 0, false, false><<<dim3(16 * 64), 256, 0, stream>>>(
        tmp2, HDIM, Wf2T, 128, 1024, bf2, nullptr, 0, x_trb, DDIM, 128, 16);
    // G5: db = x_trb @ [W1|W2|W3] + b (softplus<1024) M=4096 N=1056(pad 1088) K=1024, 1088 blk
    mm<64, 5, false, true><<<dim3(17 * 64), 256, 0, stream>>>(
        x_trb, DDIM, WbigT, 1024, NBIG, bias_big, nullptr, 0, db, NBIG, 1024, 17);

    final_k<<<dim3(MROWS), 256, 0, stream>>>(x_trb, db, Amat, h0, h0mask, out, last_h);
}

// Round 6
// 86.664 us; speedup vs baseline: 10.6141x; 1.0308x over previous
//
#include <hip/hip_runtime.h>
#include <cmath>

#define B_SZ 2
#define LSEQ 2048
#define DDIM 1024
#define NDIM 16
#define HDIM 128
#define MROWS (B_SZ * LSEQ)    // 4096
#define NBIG (DDIM + 2 * NDIM) // 1056
#define NPAD 1088              // NBIG padded to 64

typedef __bf16 bf16x8 __attribute__((ext_vector_type(8)));
typedef __bf16 bf16x4 __attribute__((ext_vector_type(4)));
typedef float f32x4 __attribute__((ext_vector_type(4)));

// async global->LDS, 16B/lane; LDS dest = wave-uniform base + lane*16
__device__ __forceinline__ void glds16(const __bf16* g, __bf16* l) {
    __builtin_amdgcn_global_load_lds(
        (const __attribute__((address_space(1))) unsigned int*)g,
        (__attribute__((address_space(3))) unsigned int*)l, 16, 0, 0);
}

// ---------------------------------------------------------------------------
// Fused preprocessing: weight transpose+cast, bias pack, x cast, h0 mask.
// ---------------------------------------------------------------------------
__device__ __forceinline__ void tcast_tile(const float* __restrict__ in,
                                           __bf16* __restrict__ out, int K, int N,
                                           int bx, int by, float (*t)[33]) {
    int tx = threadIdx.x & 31, ty = threadIdx.x >> 5;
    int n0 = bx * 32, k0 = by * 32;
    #pragma unroll
    for (int i = 0; i < 4; ++i) {
        int k = k0 + ty + i * 8, n = n0 + tx;
        t[ty + i * 8][tx] = (k < K && n < N) ? in[(size_t)k * N + n] : 0.f;
    }
    __syncthreads();
    #pragma unroll
    for (int i = 0; i < 4; ++i) {
        int n = n0 + ty + i * 8, k = k0 + tx;
        if (n < N && k < K) out[(size_t)n * K + k] = (__bf16)t[tx][ty + i * 8];
    }
}

__global__ __launch_bounds__(256) void pack_all(
    const float* W1, const float* W2, const float* W3, const float* Wl1,
    const float* Wl2, const float* Wf1, const float* Wf2,
    const float* b1, const float* b2, const float* b3,
    const float* x, const float* h0,
    __bf16* WbigT, __bf16* WaT, __bf16* Wf1bT, __bf16* Wl2T, __bf16* Wf2T,
    float* bias_big, __bf16* x_bf, unsigned* h0mask) {
    __shared__ float t[32][33];
    const int bx = blockIdx.x, by = blockIdx.y, z = blockIdx.z;
    const int tid = threadIdx.x;
    switch (z) {
        case 0: tcast_tile(W1, WbigT, 1024, 1024, bx, by, t); break;
        case 1: if (bx < 4) tcast_tile(Wl1, WaT, 1024, 128, bx, by, t); break;
        case 2: if (bx < 4) tcast_tile(Wf1, WaT + 128 * 1024, 1024, 128, bx, by, t); break;
        case 3: if (bx < 4) tcast_tile(Wf1 + (size_t)1024 * 128, Wf1bT, 1024, 128, bx, by, t); break;
        case 4: if (by < 4) tcast_tile(Wl2, Wl2T, 128, 1024, bx, by, t); break;
        case 5: if (by < 4) tcast_tile(Wf2, Wf2T, 128, 1024, bx, by, t); break;
        case 6: if (bx < 1) tcast_tile(W2, WbigT + (size_t)1024 * 1024, 1024, 16, bx, by, t); break;
        case 7: if (bx < 1) tcast_tile(W3, WbigT + (size_t)1040 * 1024, 1024, 16, bx, by, t); break;
        case 8: {
            if (by == 0 && bx < 5) {
                int i = bx * 256 + tid;
                if (i < NBIG)
                    bias_big[i] = (i < DDIM) ? b1[i]
                                : (i < DDIM + NDIM) ? b2[i - DDIM] : b3[i - DDIM - NDIM];
            }
            if (by == 1 && bx < 32) { // zero WbigT pad rows 1056..1087
                int i = bx * 256 + tid;
                #pragma unroll
                for (int r = 0; r < 4; ++r) {
                    int e = i + r * 8192;
                    if (e < 32 * 1024) WbigT[(size_t)1056 * 1024 + e] = (__bf16)0.f;
                }
            }
            break;
        }
        case 9: { // x cast fp32->bf16, 4 float4 per thread
            int id = (by * 32 + bx) * 256 + tid;
            #pragma unroll
            for (int j = 0; j < 4; ++j) {
                int e = id + j * 262144;
                float4 v = ((const float4*)x)[e];
                bf16x4 o2 = {(__bf16)v.x, (__bf16)v.y, (__bf16)v.z, (__bf16)v.w};
                ((bf16x4*)x_bf)[e] = o2;
            }
            break;
        }
        case 10: { // h0 nonzero bitmask: bit d set iff h0[d,:] has a nonzero
            if (bx == 0 && by == 0) {
                __shared__ unsigned sm[32];
                if (tid < 32) sm[tid] = 0u;
                __syncthreads();
                unsigned nib = 0;
                #pragma unroll
                for (int j = 0; j < 4; ++j) {
                    int d = tid * 4 + j;
                    const uint4* hu = (const uint4*)(h0 + d * NDIM);
                    uint4 a0 = hu[0], a1 = hu[1], a2 = hu[2], a3 = hu[3];
                    unsigned nz = a0.x | a0.y | a0.z | a0.w | a1.x | a1.y | a1.z | a1.w |
                                  a2.x | a2.y | a2.z | a2.w | a3.x | a3.y | a3.z | a3.w;
                    if (nz) nib |= (1u << j);
                }
                if (nib) atomicOr(&sm[(tid * 4) >> 5], nib << ((tid * 4) & 31));
                __syncthreads();
                if (tid < 32) h0mask[tid] = sm[tid];
            }
            break;
        }
    }
}

// ---------------------------------------------------------------------------
// bf16 MFMA GEMM, BMxBN tile, BK=64, double-buffered LDS, 2-phase prefetch.
// 4 waves 2x2; wave tile (BM/2)x(BN/2). glds16 staging, linear LDS dest;
// 8-slot XOR swizzle (chunk ^ row&7) on global source AND ds_read side
// (both-sides involution, rule #21) -> bank-balanced b128 reads.
// ACT: 0 bias, 1 relu(+prev), 2 fast-tanh, 4 split128-relu, 5 split1024-softplus
// ---------------------------------------------------------------------------
template <int BM, int BN, int ACT, bool ADD_PREV, bool GUARDN>
__global__ __launch_bounds__(256) void mm(const __bf16* __restrict__ A, int lda,
                                          const __bf16* __restrict__ Bt, int ldb, int Ntot,
                                          const float* __restrict__ bias,
                                          const __bf16* __restrict__ prev, int ldp,
                                          __bf16* __restrict__ C, int ldc, int K, int nbx) {
    constexpr int WM = BM / 2, WN = BN / 2, FM = WM / 16, FN = WN / 16;
    constexpr int ASZ = BM * 64, BSZ = BN * 64; // elems per buffer
    __shared__ __bf16 As[2 * ASZ];
    __shared__ __bf16 Bs[2 * BSZ];
    const int tid = threadIdx.x;
    const int lane = tid & 63, w = tid >> 6;
    const int wr = w >> 1, wc = w & 1;
    const int g = lane >> 4, lr = lane & 15;

    const int NB = gridDim.x;
    const int aid = (blockIdx.x & 7) * (NB >> 3) + (blockIdx.x >> 3);
    const int bn = (aid % nbx) * BN, bm = (aid / nbx) * BM;

    // staging: chunk D; LDS linear; global source chunk pre-swizzled c = pos ^ (row&7)
    auto stage = [&](int buf, int k0) {
        #pragma unroll
        for (int i = 0; i < BM / 32; ++i) {
            int D = i * 256 + tid;
            int row = D >> 3, pos = D & 7, c = pos ^ (row & 7);
            glds16(&A[(size_t)(bm + row) * lda + k0 + c * 8],
                   &As[buf * ASZ + (i * 256 + w * 64) * 8]);
        }
        #pragma unroll
        for (int i = 0; i < BN / 32; ++i) {
            int D = i * 256 + tid;
            int row = D >> 3, pos = D & 7, c = pos ^ (row & 7);
            glds16(&Bt[(size_t)(bn + row) * ldb + k0 + c * 8],
                   &Bs[buf * BSZ + (i * 256 + w * 64) * 8]);
        }
    };

    f32x4 acc[FM][FN] = {};
    const int x7 = lr & 7;
    const int ca[2] = {(g ^ x7) * 8, ((4 + g) ^ x7) * 8}; // col offset, half 0/1
    const int arow0 = wr * WM + lr;
    const int brow0 = wc * WN + lr;

    const int nt = K >> 6;
    stage(0, 0);
    __syncthreads();
    for (int t = 0; t < nt; ++t) {
        if (t + 1 < nt) stage((t + 1) & 1, (t + 1) << 6);
        const __bf16* Ab = &As[(t & 1) * ASZ];
        const __bf16* Bb = &Bs[(t & 1) * BSZ];
        bf16x8 af[FM][2], bfr[FN][2];
        #pragma unroll
        for (int m = 0; m < FM; ++m)
            #pragma unroll
            for (int h = 0; h < 2; ++h)
                af[m][h] = *(const bf16x8*)&Ab[(arow0 + m * 16) * 64 + ca[h]];
        #pragma unroll
        for (int n = 0; n < FN; ++n)
            #pragma unroll
            for (int h = 0; h < 2; ++h)
                bfr[n][h] = *(const bf16x8*)&Bb[(brow0 + n * 16) * 64 + ca[h]];
        #pragma unroll
        for (int h = 0; h < 2; ++h)
            #pragma unroll
            for (int m = 0; m < FM; ++m)
                #pragma unroll
                for (int n = 0; n < FN; ++n)
                    acc[m][n] = __builtin_amdgcn_mfma_f32_16x16x32_bf16(
                        af[m][h], bfr[n][h], acc[m][n], 0, 0, 0);
        __syncthreads(); // drains prefetch vmcnt + fences LDS reuse
    }

    // epilogue: C/D layout col=lane&15, row=(lane>>4)*4+reg
    #pragma unroll
    for (int m = 0; m < FM; ++m) {
        #pragma unroll
        for (int n = 0; n < FN; ++n) {
            #pragma unroll
            for (int r = 0; r < 4; ++r) {
                int grow = bm + wr * WM + m * 16 + g * 4 + r;
                int gcol = bn + wc * WN + n * 16 + lr;
                if (!GUARDN || gcol < Ntot) {
                    float v = acc[m][n][r];
                    if (ACT == 0) {
                        v += bias[gcol];
                    } else if (ACT == 1) {
                        v += bias[gcol];
                        if (ADD_PREV) v += (float)prev[(size_t)grow * ldp + gcol];
                        v = fmaxf(v, 0.f);
                    } else if (ACT == 2) { // fast tanh: 1 - 2/(1+e^2v)
                        v += bias[gcol];
                        float e = __expf(2.f * v);
                        v = 1.f - 2.f * __builtin_amdgcn_rcpf(e + 1.f);
                    } else if (ACT == 4) {
                        if (gcol < HDIM) v = fmaxf(v + bias[gcol], 0.f);
                    } else if (ACT == 5) {
                        v += bias[gcol];
                        if (gcol < DDIM) { // fast softplus
                            float e = __expf(-fabsf(v));
                            v = fmaxf(v, 0.f) + __logf(1.f + e);
                        }
                    }
                    C[(size_t)grow * ldc + gcol] = (__bf16)v;
                }
            }
        }
    }
}

// ---------------------------------------------------------------------------
// Final fusion; h0-zero rows resolved via precomputed 1024-bit mask.
// ---------------------------------------------------------------------------
__global__ __launch_bounds__(256) void final_k(const __bf16* __restrict__ x_tr,
                                               const __bf16* __restrict__ db,
                                               const float* __restrict__ A,
                                               const float* __restrict__ h0,
                                               const unsigned* __restrict__ h0mask,
                                               float* __restrict__ out,
                                               float* __restrict__ last_h) {
    const int row = blockIdx.x;
    const int tid = threadIdx.x;
    __shared__ float sC[NDIM], sB[NDIM];
    if (tid < NDIM) sB[tid] = (float)db[(size_t)row * NBIG + DDIM + tid];
    else if (tid >= 32 && tid < 32 + NDIM)
        sC[tid - 32] = (float)db[(size_t)row * NBIG + DDIM + NDIM + (tid - 32)];
    __syncthreads();
    float cb = 0.f;
    #pragma unroll
    for (int n = 0; n < NDIM; ++n) cb += sC[n] * sB[n];

    const int l = row & (LSEQ - 1);
    const int b = row >> 11;
    const bool is_last = (l == LSEQ - 1);

    const int d0 = tid * 4;
    bf16x4 xv = *(const bf16x4*)&x_tr[(size_t)row * DDIM + d0];
    bf16x4 dv = *(const bf16x4*)&db[(size_t)row * NBIG + d0];
    const unsigned nib = (h0mask[d0 >> 5] >> (d0 & 31)) & 0xFu;
    float4 o;
    float* op = &o.x;
    #pragma unroll
    for (int j = 0; j < 4; ++j) {
        const int d = d0 + j;
        const float xd = (float)xv[j] * (float)dv[j];
        float s = 0.f;
        if (!((nib >> j) & 1u)) {
            if (is_last) {
                #pragma unroll
                for (int n = 0; n < NDIM; ++n)
                    last_h[((size_t)b * DDIM + d) * NDIM + n] = xd * sB[n];
            }
        } else {
            const float de = (float)dv[j];
            const float* hf = h0 + d * NDIM;
            #pragma unroll
            for (int n = 0; n < NDIM; ++n) {
                float z = de * A[d * NDIM + n];
                float c = (z > 0.f) ? z : __expf(z) - 1.f;
                float da = __expf(-c);
                float h0v = hf[n];
                s += sC[n] * da * h0v;
                if (is_last)
                    last_h[((size_t)b * DDIM + d) * NDIM + n] = da * h0v + xd * sB[n];
            }
        }
        op[j] = xd * cb + s;
    }
    *(float4*)&out[(size_t)row * DDIM + d0] = o;
}

extern "C" void kernel_launch(void* const* d_in, const int* in_sizes, int n_in,
                              void* d_out, int out_size, void* d_ws, size_t ws_size,
                              hipStream_t stream) {
    const float* x   = (const float*)d_in[0];
    const float* W1  = (const float*)d_in[1];
    const float* b1  = (const float*)d_in[2];
    const float* W2  = (const float*)d_in[3];
    const float* b2  = (const float*)d_in[4];
    const float* W3  = (const float*)d_in[5];
    const float* b3  = (const float*)d_in[6];
    const float* Wl1 = (const float*)d_in[7];
    const float* bl1 = (const float*)d_in[8];
    const float* Wl2 = (const float*)d_in[9];
    const float* bl2 = (const float*)d_in[10];
    const float* Wf1 = (const float*)d_in[11];
    const float* bf1 = (const float*)d_in[12];
    const float* Wf2 = (const float*)d_in[13];
    const float* bf2 = (const float*)d_in[14];
    const float* h0  = (const float*)d_in[15];
    const float* Amat= (const float*)d_in[16];

    float* out    = (float*)d_out;
    float* last_h = (float*)d_out + (size_t)MROWS * DDIM;

    __bf16* wsb = (__bf16*)d_ws;
    size_t o = 0;
    auto alloc = [&](size_t n) { __bf16* p = wsb + o; o += n; return p; };
    __bf16* x_bf   = alloc((size_t)MROWS * DDIM);   // reused as x_trb after G1
    __bf16* WaT    = alloc(256 * 1024);             // [Wl1 | Wf1_top]^T
    __bf16* Wf1bT  = alloc(128 * 1024);
    __bf16* Wl2T   = alloc(1024 * 128);
    __bf16* Wf2T   = alloc(1024 * 128);
    __bf16* WbigT  = alloc((size_t)NPAD * 1024);    // [W1 | W2 | W3 | pad]^T
    __bf16* tmp12  = alloc((size_t)MROWS * 256);    // [relu(x@Wl1+bl1) | x@Wf1_top]
    __bf16* lifted = alloc((size_t)MROWS * DDIM);
    __bf16* tmp2   = alloc((size_t)MROWS * HDIM);
    __bf16* db     = alloc((size_t)MROWS * NBIG);   // [delta | Bm | Cm]
    float*  bias_big = (float*)(wsb + o); o += 2 * NPAD;
    unsigned* h0mask = (unsigned*)(wsb + o);
    __bf16* x_trb  = x_bf;

    pack_all<<<dim3(32, 32, 11), 256, 0, stream>>>(W1, W2, W3, Wl1, Wl2, Wf1, Wf2,
                                                   b1, b2, b3, x, h0,
                                                   WbigT, WaT, Wf1bT, Wl2T, Wf2T,
                                                   bias_big, x_bf, h0mask);

    // G1: tmp12 = [relu(x@Wl1+bl1) | x@Wf1_top]     M=4096 N=256 K=1024, 256 blk
    mm<64, 64, 4, false, false><<<dim3(4 * 64), 256, 0, stream>>>(
        x_bf, DDIM, WaT, 1024, 256, bl1, nullptr, 0, tmp12, 256, 1024, 4);
    // G2: lifted = tanh(tmp12[:,:128] @ Wl2 + bl2)  M=4096 N=1024 K=128, 512 blk
    mm<64, 128, 2, false, false><<<dim3(8 * 64), 256, 0, stream>>>(
        tmp12, 256, Wl2T, 128, 1024, bl2, nullptr, 0, lifted, DDIM, 128, 8);
    // G3: tmp2 = relu(lifted@Wf1_bot + bf1 + tmp12[:,128:]) M=4096 N=128 K=1024, 256 blk
    mm<32, 64, 1, true, false><<<dim3(2 * 128), 256, 0, stream>>>(
        lifted, DDIM, Wf1bT, 1024, 128, bf1, tmp12 + 128, 256, tmp2, HDIM, 1024, 2);
    // G4: x_trb = tmp2 @ Wf2 + bf2                  M=4096 N=1024 K=128, 512 blk
    mm<64, 128, 0, false, false><<<dim3(8 * 64), 256, 0, stream>>>(
        tmp2, HDIM, Wf2T, 128, 1024, bf2, nullptr, 0, x_trb, DDIM, 128, 8);
    // G5: db = x_trb @ [W1|W2|W3] + b (softplus<1024) M=4096 N=1056(pad 1088) K=1024, 544 blk
    mm<128, 64, 5, false, true><<<dim3(17 * 32), 256, 0, stream>>>(
        x_trb, DDIM, WbigT, 1024, NBIG, bias_big, nullptr, 0, db, NBIG, 1024, 17);

    final_k<<<dim3(MROWS), 256, 0, stream>>>(x_trb, db, Amat, h0, h0mask, out, last_h);
}